// Round 1
// baseline (1583.724 us; speedup 1.0000x reference)
//
#include <hip/hip_runtime.h>

// Problem constants (derived from in_sizes at launch for robustness)
//   x_stroke [N,6] f32; ei_temp [2,Et] i32 (sum agg); ei_inter [2,Ei] i32 (mean agg)
//   head 6->32, 3 blocks 32->32 residual, last 32->64 with residual projection.
// Algebraic restructure: segment_agg(x @ W) == segment_agg(x) @ W, so we
// aggregate RAW features (6 or 32 ch) once per layer and fuse Wt/Wi/Wr into one
// per-node mini-GEMM. Inter aggregation is gather-based over a CSR built per
// call (atomics only for degree-count + slot-fill of int32 indices).

// ---------------- CSR build ----------------

__global__ void k_deg(const int* __restrict__ dst, int E, int* __restrict__ deg) {
    int i = blockIdx.x * blockDim.x + threadIdx.x;
    if (i < E) atomicAdd(&deg[dst[i]], 1);
}

// Single-block exclusive scan over N (~100k) elements; also emits cursor copy
// and 1/max(deg,1) for the mean.
__global__ void k_scan(const int* __restrict__ deg, int N, int* __restrict__ rs,
                       int* __restrict__ cur, float* __restrict__ invdeg) {
    const int T = 1024;
    __shared__ int sh[T];
    int t = threadIdx.x;
    int chunk = (N + T - 1) / T;
    int lo = t * chunk;
    int hi = min(lo + chunk, N);
    int sum = 0;
    for (int i = lo; i < hi; ++i) sum += deg[i];
    sh[t] = sum;
    __syncthreads();
    // inclusive Hillis-Steele scan of per-chunk sums
    for (int off = 1; off < T; off <<= 1) {
        int v = (t >= off) ? sh[t - off] : 0;
        __syncthreads();
        sh[t] += v;
        __syncthreads();
    }
    int run = (t == 0) ? 0 : sh[t - 1];
    for (int i = lo; i < hi; ++i) {
        rs[i] = run;
        cur[i] = run;
        int d = deg[i];
        invdeg[i] = 1.0f / (float)max(d, 1);
        run += d;
    }
    if (hi == N) rs[N] = run;   // every thread with hi==N has run==total
}

__global__ void k_fill(const int* __restrict__ src, const int* __restrict__ dst, int E,
                       int* __restrict__ cur, int* __restrict__ csr) {
    int i = blockIdx.x * blockDim.x + threadIdx.x;
    if (i < E) {
        int d = dst[i];
        int p = atomicAdd(&cur[d], 1);
        csr[p] = src[i];
    }
}

// ---------------- aggregation ----------------

// temp relation (sum): only 100k edges -> scatter atomics are cheap.
// LP lanes per edge (pow2 >= CH), lane = channel.
template <int CH, int LP>
__global__ void k_scatter_sum(const float* __restrict__ x, const int* __restrict__ src,
                              const int* __restrict__ dst, int E, float* __restrict__ agg) {
    int tid = blockIdx.x * blockDim.x + threadIdx.x;
    int e = tid >> (LP == 8 ? 3 : 5);
    int c = tid & (LP - 1);
    if (e >= E) return;
    int s = src[e];
    int d = dst[e];
    if (c < CH) atomicAdd(&agg[d * CH + c], x[s * CH + c]);
}

// inter relation (mean): gather over CSR. LP lanes per destination, lane = channel.
// csr entries are cooperatively loaded LP at a time and broadcast via shfl.
template <int CH, int LP>
__global__ void k_gather_mean(const float* __restrict__ x, const int* __restrict__ rs,
                              const int* __restrict__ csr, const float* __restrict__ invdeg,
                              float* __restrict__ agg, int N) {
    int tid = blockIdx.x * blockDim.x + threadIdx.x;
    int g = tid >> (LP == 8 ? 3 : 5);
    int c = tid & (LP - 1);
    if (g >= N) return;
    int e0 = rs[g];
    int e1 = rs[g + 1];
    float acc = 0.0f;
    for (int e = e0; e < e1; e += LP) {
        int n = min(LP, e1 - e);
        int myS = (c < n) ? csr[e + c] : 0;
        for (int j = 0; j < n; ++j) {
            int s = __shfl(myS, j, LP);
            if (c < CH) acc += x[s * CH + c];
        }
    }
    if (c < CH) agg[g * CH + c] = acc * invdeg[g];
}

// ---------------- per-node fused mini-GEMM layers ----------------

// head: K=6 inputs, 32 outputs. 32 lanes per node, lane = output channel.
__global__ void k_node_head(const float* __restrict__ x, const float* __restrict__ aggt,
                            const float* __restrict__ aggi, const float* __restrict__ Wt,
                            const float* __restrict__ Wi, const float* __restrict__ Wr,
                            const float* __restrict__ b, float* __restrict__ h, int N) {
    int tid = blockIdx.x * blockDim.x + threadIdx.x;
    int n = tid >> 5, c = tid & 31;
    if (n >= N) return;
    float vt = (c < 6) ? aggt[n * 6 + c] : 0.0f;
    float vi = (c < 6) ? aggi[n * 6 + c] : 0.0f;
    float vx = (c < 6) ? x[n * 6 + c] : 0.0f;
    float acc = b[c];
#pragma unroll
    for (int k = 0; k < 6; ++k) {
        float at = __shfl(vt, k, 32);
        float ai = __shfl(vi, k, 32);
        float ax = __shfl(vx, k, 32);
        acc += at * Wt[k * 32 + c] + ai * Wi[k * 32 + c] + ax * Wr[k * 32 + c];
    }
    h[n * 32 + c] = fmaxf(acc, 0.0f);
}

// hidden residual block: K=32 -> 32 out, hout = relu(conv) + hin
__global__ void k_node_blk(const float* __restrict__ hin, const float* __restrict__ aggt,
                           const float* __restrict__ aggi, const float* __restrict__ Wt,
                           const float* __restrict__ Wi, const float* __restrict__ Wr,
                           const float* __restrict__ b, float* __restrict__ hout, int N) {
    int tid = blockIdx.x * blockDim.x + threadIdx.x;
    int n = tid >> 5, c = tid & 31;
    if (n >= N) return;
    float vt = aggt[n * 32 + c];
    float vi = aggi[n * 32 + c];
    float vh = hin[n * 32 + c];
    float acc = b[c];
    for (int k = 0; k < 32; ++k) {
        acc += __shfl(vt, k, 32) * Wt[k * 32 + c] + __shfl(vi, k, 32) * Wi[k * 32 + c] +
               __shfl(vh, k, 32) * Wr[k * 32 + c];
    }
    hout[n * 32 + c] = fmaxf(acc, 0.0f) + vh;
}

// last block: K=32 -> 64 out, out = relu(conv) + hin @ proj. 64 lanes per node.
__global__ void k_node_last(const float* __restrict__ hin, const float* __restrict__ aggt,
                            const float* __restrict__ aggi, const float* __restrict__ Wt,
                            const float* __restrict__ Wi, const float* __restrict__ Wr,
                            const float* __restrict__ b, const float* __restrict__ proj,
                            float* __restrict__ out, int N) {
    int tid = blockIdx.x * blockDim.x + threadIdx.x;
    int n = tid >> 6, c = tid & 63;
    if (n >= N) return;
    float vt = (c < 32) ? aggt[n * 32 + c] : 0.0f;
    float vi = (c < 32) ? aggi[n * 32 + c] : 0.0f;
    float vh = (c < 32) ? hin[n * 32 + c] : 0.0f;
    float acc = b[c];
    float accp = 0.0f;
    for (int k = 0; k < 32; ++k) {
        float at = __shfl(vt, k, 64);
        float ai = __shfl(vi, k, 64);
        float ah = __shfl(vh, k, 64);
        acc += at * Wt[k * 64 + c] + ai * Wi[k * 64 + c] + ah * Wr[k * 64 + c];
        accp += ah * proj[k * 64 + c];
    }
    out[n * 64 + c] = fmaxf(acc, 0.0f) + accp;
}

// ---------------- launch ----------------

static inline size_t align256(size_t x) { return (x + 255) & ~(size_t)255; }

extern "C" void kernel_launch(void* const* d_in, const int* in_sizes, int n_in,
                              void* d_out, int out_size, void* d_ws, size_t ws_size,
                              hipStream_t stream) {
    const float* x_stroke = (const float*)d_in[0];
    const int* ei_temp = (const int*)d_in[1];
    const int* ei_inter = (const int*)d_in[2];
    const float* head_Wt = (const float*)d_in[3];
    const float* head_Wi = (const float*)d_in[4];
    const float* head_Wr = (const float*)d_in[5];
    const float* head_b = (const float*)d_in[6];
    const float* blk_Wt = (const float*)d_in[7];
    const float* blk_Wi = (const float*)d_in[8];
    const float* blk_Wr = (const float*)d_in[9];
    const float* blk_b = (const float*)d_in[10];
    const float* last_Wt = (const float*)d_in[11];
    const float* last_Wi = (const float*)d_in[12];
    const float* last_Wr = (const float*)d_in[13];
    const float* last_b = (const float*)d_in[14];
    const float* last_proj = (const float*)d_in[15];

    const int N = in_sizes[0] / 6;
    const int Et = in_sizes[1] / 2;
    const int Ei = in_sizes[2] / 2;

    const int* temp_src = ei_temp;
    const int* temp_dst = ei_temp + Et;
    const int* int_src = ei_inter;
    const int* int_dst = ei_inter + Ei;

    // workspace carve-up
    char* p = (char*)d_ws;
    size_t off = 0;
    auto carve = [&](size_t bytes) {
        char* r = p + off;
        off = align256(off + bytes);
        return r;
    };
    int* deg = (int*)carve((size_t)N * 4);
    int* rs = (int*)carve((size_t)(N + 1) * 4);
    int* cur = (int*)carve((size_t)N * 4);
    float* invdeg = (float*)carve((size_t)N * 4);
    int* csr = (int*)carve((size_t)Ei * 4);
    float* bufA = (float*)carve((size_t)N * 32 * 4);
    float* bufB = (float*)carve((size_t)N * 32 * 4);
    float* bufC = (float*)carve((size_t)N * 32 * 4);
    float* bufD = (float*)carve((size_t)N * 32 * 4);
    (void)ws_size;

    const int B = 256;
    auto blocks = [&](long long work) { return (int)((work + B - 1) / B); };

    // ---- CSR build (inter relation only; temp uses cheap scatter) ----
    hipMemsetAsync(deg, 0, (size_t)N * 4, stream);
    k_deg<<<blocks(Ei), B, 0, stream>>>(int_dst, Ei, deg);
    k_scan<<<1, 1024, 0, stream>>>(deg, N, rs, cur, invdeg);
    k_fill<<<blocks(Ei), B, 0, stream>>>(int_src, int_dst, Ei, cur, csr);

    // ---- head layer (6 ch agg) ----
    hipMemsetAsync(bufB, 0, (size_t)N * 6 * 4, stream);
    k_scatter_sum<6, 8><<<blocks((long long)Et * 8), B, 0, stream>>>(x_stroke, temp_src, temp_dst, Et, bufB);
    k_gather_mean<6, 8><<<blocks((long long)N * 8), B, 0, stream>>>(x_stroke, rs, csr, invdeg, bufC, N);
    k_node_head<<<blocks((long long)N * 32), B, 0, stream>>>(x_stroke, bufB, bufC, head_Wt, head_Wi,
                                                             head_Wr, head_b, bufA, N);

    // ---- 3 hidden residual blocks: h alternates A -> D -> A -> D ----
    float* hin = bufA;
    float* hout = bufD;
    for (int i = 0; i < 3; ++i) {
        hipMemsetAsync(bufB, 0, (size_t)N * 32 * 4, stream);
        k_scatter_sum<32, 32><<<blocks((long long)Et * 32), B, 0, stream>>>(hin, temp_src, temp_dst, Et, bufB);
        k_gather_mean<32, 32><<<blocks((long long)N * 32), B, 0, stream>>>(hin, rs, csr, invdeg, bufC, N);
        k_node_blk<<<blocks((long long)N * 32), B, 0, stream>>>(
            hin, bufB, bufC, blk_Wt + (size_t)i * 32 * 32, blk_Wi + (size_t)i * 32 * 32,
            blk_Wr + (size_t)i * 32 * 32, blk_b + (size_t)i * 32, hout, N);
        float* t = hin; hin = hout; hout = t;
    }

    // ---- last layer (aggregate 32-ch hin, expand to 64 out) ----
    hipMemsetAsync(bufB, 0, (size_t)N * 32 * 4, stream);
    k_scatter_sum<32, 32><<<blocks((long long)Et * 32), B, 0, stream>>>(hin, temp_src, temp_dst, Et, bufB);
    k_gather_mean<32, 32><<<blocks((long long)N * 32), B, 0, stream>>>(hin, rs, csr, invdeg, bufC, N);
    k_node_last<<<blocks((long long)N * 64), B, 0, stream>>>(hin, bufB, bufC, last_Wt, last_Wi, last_Wr,
                                                             last_b, last_proj, (float*)d_out, N);
}

// Round 2
// 992.875 us; speedup vs baseline: 1.5951x; 1.5951x over previous
//
#include <hip/hip_runtime.h>

// Hetero-GNN: 5 layers of relu(segsum_temp(x) @ Wt + segmean_inter(x) @ Wi + x @ Wr + b)
// (aggregation commuted with the matmuls: aggregate RAW features, then one fused
// per-node mini-GEMM per layer).
//
// Inter aggregation (3.2M edges, mean) and temp aggregation (100k edges, sum) use
// PADDED CSR by destination, built in ONE atomic pass per relation (no deg pass,
// no scan). Capacity Ci=64 / Ct=16 slots per node; overflow edges (expected ~0 for
// Poisson(32)/Poisson(1) degrees) go to a small list and are applied per layer with
// fp32 atomics — correct for any input.
// Gather: one 64-lane wave per destination; lane = (row_slot r, float4 quarter q);
// one dwordx4 load instruction covers 64/CHV edge-rows.

#define VO 8192  // overflow list capacity (pairs) per relation

__device__ inline void f4add(float4& a, const float4& v) {
    a.x += v.x; a.y += v.y; a.z += v.z; a.w += v.w;
}

// ---------------- padded CSR build (one pass) ----------------

__global__ void k_fill2(const int* __restrict__ src, const int* __restrict__ dst, int E,
                        int* __restrict__ cnt, int* __restrict__ csr, int C,
                        int* __restrict__ ovf, int* __restrict__ ovf_n) {
    int i = blockIdx.x * blockDim.x + threadIdx.x;
    if (i >= E) return;
    int s = src[i];
    int d = dst[i];
    int slot = atomicAdd(&cnt[d], 1);
    if (slot < C) {
        csr[(size_t)d * C + slot] = s;
    } else {
        int p = atomicAdd(ovf_n, 1);
        if (p < VO) { ovf[2 * p] = d; ovf[2 * p + 1] = s; }
    }
}

// pad x [N,6] -> x8 [N,8] (zeros in cols 6,7) so gather can use float4 rows
__global__ void k_pad_x(const float* __restrict__ x, float* __restrict__ x8, int N) {
    int i = blockIdx.x * blockDim.x + threadIdx.x;
    if (i >= N * 8) return;
    int n = i >> 3, c = i & 7;
    x8[i] = (c < 6) ? x[n * 6 + c] : 0.0f;
}

// ---------------- gather (both relations), wave per destination ----------------
// CHV = float4s per feature row (2 -> 8ch padded head, 8 -> 32ch hidden).

template <int CHV>
__global__ void k_gather2(const float* __restrict__ x,
                          const int* __restrict__ csr_i, const int* __restrict__ cnt_i, int Ci,
                          const int* __restrict__ csr_t, const int* __restrict__ cnt_t, int Ct,
                          float* __restrict__ aggi, float* __restrict__ aggt, int N) {
    const int R = 64 / CHV;             // rows in flight per wave
    int tid = blockIdx.x * blockDim.x + threadIdx.x;
    int g = tid >> 6;                   // wave id = destination node
    int lane = threadIdx.x & 63;
    if (g >= N) return;
    int q = lane % CHV;                 // which float4 of the row
    int r = lane / CHV;                 // row slot 0..R-1

    float4 acc_i = make_float4(0.f, 0.f, 0.f, 0.f);
    float4 acc_t = make_float4(0.f, 0.f, 0.f, 0.f);

    // inter relation (mean)
    int ci_full = cnt_i[g];
    int ci = min(ci_full, Ci);
    for (int base = 0; base < ci; base += 64) {
        int nb = min(64, ci - base);
        int sv = (lane < nb) ? csr_i[(size_t)g * Ci + base + lane] : 0;
        int nit = (nb + R - 1) / R;
        for (int it = 0; it < nit; ++it) {
            int el = it * R + r;
            int s = __shfl(sv, el, 64);
            if (el < nb) {
                const float4 v = *(const float4*)(x + (size_t)s * (CHV * 4) + q * 4);
                f4add(acc_i, v);
            }
        }
    }

    // temp relation (sum)
    int ct = min(cnt_t[g], Ct);
    for (int base = 0; base < ct; base += 64) {
        int nb = min(64, ct - base);
        int sv = (lane < nb) ? csr_t[(size_t)g * Ct + base + lane] : 0;
        int nit = (nb + R - 1) / R;
        for (int it = 0; it < nit; ++it) {
            int el = it * R + r;
            int s = __shfl(sv, el, 64);
            if (el < nb) {
                const float4 v = *(const float4*)(x + (size_t)s * (CHV * 4) + q * 4);
                f4add(acc_t, v);
            }
        }
    }

    // reduce over row slots (xor strides CHV, 2*CHV, ..., 32)
#pragma unroll
    for (int st = CHV; st < 64; st <<= 1) {
        acc_i.x += __shfl_xor(acc_i.x, st, 64);
        acc_i.y += __shfl_xor(acc_i.y, st, 64);
        acc_i.z += __shfl_xor(acc_i.z, st, 64);
        acc_i.w += __shfl_xor(acc_i.w, st, 64);
        acc_t.x += __shfl_xor(acc_t.x, st, 64);
        acc_t.y += __shfl_xor(acc_t.y, st, 64);
        acc_t.z += __shfl_xor(acc_t.z, st, 64);
        acc_t.w += __shfl_xor(acc_t.w, st, 64);
    }

    float inv = 1.0f / (float)max(ci_full, 1);
    if (r == 0) {
        float4 o = make_float4(acc_i.x * inv, acc_i.y * inv, acc_i.z * inv, acc_i.w * inv);
        *(float4*)(aggi + (size_t)g * (CHV * 4) + q * 4) = o;
    }
    if (r == 1) {
        *(float4*)(aggt + (size_t)g * (CHV * 4) + q * 4) = acc_t;
    }
}

// overflow edges: apply with atomics after the gather. CH = row stride (8 or 32).
template <int CH>
__global__ void k_ovf(const float* __restrict__ x,
                      const int* __restrict__ ovf_i, const int* __restrict__ ovfn_i,
                      const int* __restrict__ cnt_i,
                      const int* __restrict__ ovf_t, const int* __restrict__ ovfn_t,
                      float* __restrict__ aggi, float* __restrict__ aggt) {
    int tid = blockIdx.x * blockDim.x + threadIdx.x;
    int rel = tid / (VO * CH);
    int j = tid % (VO * CH);
    int idx = j / CH;
    int c = j % CH;
    if (rel == 0) {
        int n = min(*ovfn_i, VO);
        if (idx < n) {
            int d = ovf_i[2 * idx], s = ovf_i[2 * idx + 1];
            float inv = 1.0f / (float)max(cnt_i[d], 1);
            atomicAdd(&aggi[(size_t)d * CH + c], x[(size_t)s * CH + c] * inv);
        }
    } else if (rel == 1) {
        int n = min(*ovfn_t, VO);
        if (idx < n) {
            int d = ovf_t[2 * idx], s = ovf_t[2 * idx + 1];
            atomicAdd(&aggt[(size_t)d * CH + c], x[(size_t)s * CH + c]);
        }
    }
}

// ---------------- per-node fused mini-GEMM layers ----------------

// head: K=6 inputs (aggs padded to stride 8), 32 outputs. 32 lanes/node.
__global__ void k_node_head(const float* __restrict__ x, const float* __restrict__ aggt,
                            const float* __restrict__ aggi, const float* __restrict__ Wt,
                            const float* __restrict__ Wi, const float* __restrict__ Wr,
                            const float* __restrict__ b, float* __restrict__ h, int N) {
    int tid = blockIdx.x * blockDim.x + threadIdx.x;
    int n = tid >> 5, c = tid & 31;
    if (n >= N) return;
    float vt = (c < 6) ? aggt[n * 8 + c] : 0.0f;
    float vi = (c < 6) ? aggi[n * 8 + c] : 0.0f;
    float vx = (c < 6) ? x[n * 6 + c] : 0.0f;
    float acc = b[c];
#pragma unroll
    for (int k = 0; k < 6; ++k) {
        float at = __shfl(vt, k, 32);
        float ai = __shfl(vi, k, 32);
        float ax = __shfl(vx, k, 32);
        acc += at * Wt[k * 32 + c] + ai * Wi[k * 32 + c] + ax * Wr[k * 32 + c];
    }
    h[n * 32 + c] = fmaxf(acc, 0.0f);
}

// hidden residual block: K=32 -> 32 out, hout = relu(conv) + hin
__global__ void k_node_blk(const float* __restrict__ hin, const float* __restrict__ aggt,
                           const float* __restrict__ aggi, const float* __restrict__ Wt,
                           const float* __restrict__ Wi, const float* __restrict__ Wr,
                           const float* __restrict__ b, float* __restrict__ hout, int N) {
    int tid = blockIdx.x * blockDim.x + threadIdx.x;
    int n = tid >> 5, c = tid & 31;
    if (n >= N) return;
    float vt = aggt[n * 32 + c];
    float vi = aggi[n * 32 + c];
    float vh = hin[n * 32 + c];
    float acc = b[c];
    for (int k = 0; k < 32; ++k) {
        acc += __shfl(vt, k, 32) * Wt[k * 32 + c] + __shfl(vi, k, 32) * Wi[k * 32 + c] +
               __shfl(vh, k, 32) * Wr[k * 32 + c];
    }
    hout[n * 32 + c] = fmaxf(acc, 0.0f) + vh;
}

// last block: K=32 -> 64 out, out = relu(conv) + hin @ proj. 64 lanes/node.
__global__ void k_node_last(const float* __restrict__ hin, const float* __restrict__ aggt,
                            const float* __restrict__ aggi, const float* __restrict__ Wt,
                            const float* __restrict__ Wi, const float* __restrict__ Wr,
                            const float* __restrict__ b, const float* __restrict__ proj,
                            float* __restrict__ out, int N) {
    int tid = blockIdx.x * blockDim.x + threadIdx.x;
    int n = tid >> 6, c = tid & 63;
    if (n >= N) return;
    float vt = (c < 32) ? aggt[n * 32 + c] : 0.0f;
    float vi = (c < 32) ? aggi[n * 32 + c] : 0.0f;
    float vh = (c < 32) ? hin[n * 32 + c] : 0.0f;
    float acc = b[c];
    float accp = 0.0f;
    for (int k = 0; k < 32; ++k) {
        float at = __shfl(vt, k, 64);
        float ai = __shfl(vi, k, 64);
        float ah = __shfl(vh, k, 64);
        acc += at * Wt[k * 64 + c] + ai * Wi[k * 64 + c] + ah * Wr[k * 64 + c];
        accp += ah * proj[k * 64 + c];
    }
    out[n * 64 + c] = fmaxf(acc, 0.0f) + accp;
}

// ---------------- launch ----------------

static inline size_t align256(size_t x) { return (x + 255) & ~(size_t)255; }

extern "C" void kernel_launch(void* const* d_in, const int* in_sizes, int n_in,
                              void* d_out, int out_size, void* d_ws, size_t ws_size,
                              hipStream_t stream) {
    const float* x_stroke = (const float*)d_in[0];
    const int* ei_temp = (const int*)d_in[1];
    const int* ei_inter = (const int*)d_in[2];
    const float* head_Wt = (const float*)d_in[3];
    const float* head_Wi = (const float*)d_in[4];
    const float* head_Wr = (const float*)d_in[5];
    const float* head_b = (const float*)d_in[6];
    const float* blk_Wt = (const float*)d_in[7];
    const float* blk_Wi = (const float*)d_in[8];
    const float* blk_Wr = (const float*)d_in[9];
    const float* blk_b = (const float*)d_in[10];
    const float* last_Wt = (const float*)d_in[11];
    const float* last_Wi = (const float*)d_in[12];
    const float* last_Wr = (const float*)d_in[13];
    const float* last_b = (const float*)d_in[14];
    const float* last_proj = (const float*)d_in[15];

    const int N = in_sizes[0] / 6;
    const int Et = in_sizes[1] / 2;
    const int Ei = in_sizes[2] / 2;

    const int* temp_src = ei_temp;
    const int* temp_dst = ei_temp + Et;
    const int* int_src = ei_inter;
    const int* int_dst = ei_inter + Ei;

    // ---- workspace carve-up ----
    char* p = (char*)d_ws;
    size_t off = 0;
    auto carve = [&](size_t bytes) {
        char* r = p + off;
        off = align256(off + bytes);
        return r;
    };
    int* cnt_i = (int*)carve((size_t)N * 4);
    int* cnt_t = (int*)carve((size_t)N * 4);
    int* ovfn = (int*)carve(2 * 4);          // [0]=inter, [1]=temp
    int* ovf_i = (int*)carve((size_t)VO * 8);
    int* ovf_t = (int*)carve((size_t)VO * 8);
    float* x8 = (float*)carve((size_t)N * 8 * 4);
    float* bufA = (float*)carve((size_t)N * 32 * 4);
    float* bufB = (float*)carve((size_t)N * 32 * 4);  // aggi
    float* bufC = (float*)carve((size_t)N * 32 * 4);  // aggt
    float* bufD = (float*)carve((size_t)N * 32 * 4);
    // capacities: prefer Ci=64/Ct=16; degrade if workspace is tight
    int Ct = 16, Ci = 64;
    {
        size_t need = off + (size_t)N * (Ct + Ci) * 4;
        if (need > ws_size) { Ct = 8; Ci = 48; }
        size_t avail = (ws_size > off) ? (ws_size - off) : 0;
        size_t cap = avail / ((size_t)N * 4);
        if ((size_t)(Ct + Ci) > cap) {
            Ct = 8;
            Ci = (cap > 8) ? (int)(cap - 8) : 4;
            if (Ci > 64) Ci = 64;
        }
    }
    int* csr_t = (int*)carve((size_t)N * Ct * 4);
    int* csr_i = (int*)carve((size_t)N * Ci * 4);

    const int B = 256;
    auto blocks = [&](long long work) { return (int)((work + B - 1) / B); };

    // ---- CSR build (one pass per relation) ----
    hipMemsetAsync(cnt_i, 0, (size_t)N * 4, stream);
    hipMemsetAsync(cnt_t, 0, (size_t)N * 4, stream);
    hipMemsetAsync(ovfn, 0, 2 * 4, stream);
    k_fill2<<<blocks(Ei), B, 0, stream>>>(int_src, int_dst, Ei, cnt_i, csr_i, Ci, ovf_i, &ovfn[0]);
    k_fill2<<<blocks(Et), B, 0, stream>>>(temp_src, temp_dst, Et, cnt_t, csr_t, Ct, ovf_t, &ovfn[1]);
    k_pad_x<<<blocks((long long)N * 8), B, 0, stream>>>(x_stroke, x8, N);

    // ---- head layer (8ch padded) ----
    k_gather2<2><<<blocks((long long)N * 64), B, 0, stream>>>(x8, csr_i, cnt_i, Ci, csr_t, cnt_t, Ct,
                                                              bufB, bufC, N);
    k_ovf<8><<<blocks((long long)2 * VO * 8), B, 0, stream>>>(x8, ovf_i, &ovfn[0], cnt_i, ovf_t,
                                                              &ovfn[1], bufB, bufC);
    k_node_head<<<blocks((long long)N * 32), B, 0, stream>>>(x_stroke, bufC, bufB, head_Wt, head_Wi,
                                                             head_Wr, head_b, bufA, N);

    // ---- 3 hidden residual blocks ----
    float* hin = bufA;
    float* hout = bufD;
    for (int i = 0; i < 3; ++i) {
        k_gather2<8><<<blocks((long long)N * 64), B, 0, stream>>>(hin, csr_i, cnt_i, Ci, csr_t, cnt_t,
                                                                  Ct, bufB, bufC, N);
        k_ovf<32><<<blocks((long long)2 * VO * 32), B, 0, stream>>>(hin, ovf_i, &ovfn[0], cnt_i, ovf_t,
                                                                    &ovfn[1], bufB, bufC);
        k_node_blk<<<blocks((long long)N * 32), B, 0, stream>>>(
            hin, bufC, bufB, blk_Wt + (size_t)i * 32 * 32, blk_Wi + (size_t)i * 32 * 32,
            blk_Wr + (size_t)i * 32 * 32, blk_b + (size_t)i * 32, hout, N);
        float* t = hin; hin = hout; hout = t;
    }

    // ---- last layer ----
    k_gather2<8><<<blocks((long long)N * 64), B, 0, stream>>>(hin, csr_i, cnt_i, Ci, csr_t, cnt_t, Ct,
                                                              bufB, bufC, N);
    k_ovf<32><<<blocks((long long)2 * VO * 32), B, 0, stream>>>(hin, ovf_i, &ovfn[0], cnt_i, ovf_t,
                                                                &ovfn[1], bufB, bufC);
    k_node_last<<<blocks((long long)N * 64), B, 0, stream>>>(hin, bufC, bufB, last_Wt, last_Wi,
                                                             last_Wr, last_b, last_proj,
                                                             (float*)d_out, N);
}

// Round 3
// 765.894 us; speedup vs baseline: 2.0678x; 1.2964x over previous
//
#include <hip/hip_runtime.h>

// Hetero-GNN: 5 layers of relu(segsum_temp(x) @ Wt + segmean_inter(x) @ Wi + x @ Wr + b)
// with aggregation commuted past the matmuls (aggregate RAW features, then one
// fused per-node mini-GEMM inside the SAME kernel as the gather).
//
// Inter relation (3.2M edges): padded CSR built via destination BINNING to kill
// the 15x write amplification of naive scatter:
//   hist (bucket = dst>>shift, ~782 buckets of 128 nodes) -> scan -> bucket-sorted
//   edge scatter (sequential per-bucket cursors, L2-resident line fills) ->
//   per-bucket CSR fill (writes confined to 32 KB region).
// Temp relation (100k edges): cheap one-pass atomic fill.
// Overflow (deg > capacity, expected count 0) goes to a list, applied inline in
// the gather when cnt > cap (wave-uniform branch).

#define VO 8192   // overflow list capacity (pairs) per relation
#define EPT 16    // edges per thread in k_scatter

__device__ inline void f4add(float4& a, const float4& v) {
    a.x += v.x; a.y += v.y; a.z += v.z; a.w += v.w;
}

__device__ inline float sel4(float a, float b, float c, float d, int k) {
    return (k & 2) ? ((k & 1) ? d : c) : ((k & 1) ? b : a);
}

// ---------------- inter CSR build: hist -> scan -> scatter -> fill ----------------

__global__ void k_hist(const int* __restrict__ dst, int E, int* __restrict__ gh,
                       int NB, int shift) {
    __shared__ int sh[1024];
    for (int j = threadIdx.x; j < NB; j += blockDim.x) sh[j] = 0;
    __syncthreads();
    for (int i = blockIdx.x * blockDim.x + threadIdx.x; i < E; i += gridDim.x * blockDim.x)
        atomicAdd(&sh[dst[i] >> shift], 1);
    __syncthreads();
    for (int j = threadIdx.x; j < NB; j += blockDim.x)
        if (sh[j]) atomicAdd(&gh[j], sh[j]);
}

// single block, 1024 threads; NB <= 1024. exclusive scan -> boff[NB+1], cursor copy.
__global__ void k_scan_b(const int* __restrict__ gh, int NB, int* __restrict__ boff,
                         int* __restrict__ cur) {
    __shared__ int sh[1024];
    int t = threadIdx.x;
    sh[t] = (t < NB) ? gh[t] : 0;
    __syncthreads();
    for (int off = 1; off < 1024; off <<= 1) {
        int v = (t >= off) ? sh[t - off] : 0;
        __syncthreads();
        sh[t] += v;
        __syncthreads();
    }
    if (t < NB) {
        int ex = t ? sh[t - 1] : 0;
        boff[t] = ex;
        cur[t] = ex;
    }
    if (t == 0) boff[NB] = sh[NB - 1];
}

// bucket-sorted edge scatter with two-level cursor reservation.
__global__ void k_scatter(const int* __restrict__ src, const int* __restrict__ dst, int E,
                          int shift, int NB, int* __restrict__ cur, int2* __restrict__ ebuf) {
    __shared__ int lh[1024];
    __shared__ int lb[1024];
    int lo = blockIdx.x * (blockDim.x * EPT);
    for (int j = threadIdx.x; j < NB; j += blockDim.x) lh[j] = 0;
    __syncthreads();
    int s[EPT], d[EPT], rk[EPT];
#pragma unroll
    for (int u = 0; u < EPT; ++u) {
        int e = lo + u * blockDim.x + threadIdx.x;
        if (e < E) {
            s[u] = src[e];
            d[u] = dst[e];
            rk[u] = atomicAdd(&lh[d[u] >> shift], 1);
        }
    }
    __syncthreads();
    for (int j = threadIdx.x; j < NB; j += blockDim.x) {
        int c = lh[j];
        lb[j] = c ? atomicAdd(&cur[j], c) : 0;
    }
    __syncthreads();
#pragma unroll
    for (int u = 0; u < EPT; ++u) {
        int e = lo + u * blockDim.x + threadIdx.x;
        if (e < E) ebuf[lb[d[u] >> shift] + rk[u]] = make_int2(s[u], d[u]);
    }
}

// one block per bucket: CSR writes confined to a ~32 KB L2-resident region.
__global__ void k_fill3(const int2* __restrict__ ebuf, const int* __restrict__ boff, int NB,
                        int* __restrict__ cnt, int* __restrict__ csr, int Ci,
                        int* __restrict__ ovf, int* __restrict__ ovf_n) {
    int b = blockIdx.x;
    if (b >= NB) return;
    int lo = boff[b], hi = boff[b + 1];
    for (int e = lo + threadIdx.x; e < hi; e += blockDim.x) {
        int2 sd = ebuf[e];
        int slot = atomicAdd(&cnt[sd.y], 1);
        if (slot < Ci) {
            csr[(size_t)sd.y * Ci + slot] = sd.x;
        } else {
            int p = atomicAdd(ovf_n, 1);
            if (p < VO) { ovf[2 * p] = sd.y; ovf[2 * p + 1] = sd.x; }
        }
    }
}

// temp relation (100k edges): one-pass atomic fill is cheap enough.
__global__ void k_fill2(const int* __restrict__ src, const int* __restrict__ dst, int E,
                        int* __restrict__ cnt, int* __restrict__ csr, int C,
                        int* __restrict__ ovf, int* __restrict__ ovf_n) {
    int i = blockIdx.x * blockDim.x + threadIdx.x;
    if (i >= E) return;
    int s = src[i];
    int d = dst[i];
    int slot = atomicAdd(&cnt[d], 1);
    if (slot < C) {
        csr[(size_t)d * C + slot] = s;
    } else {
        int p = atomicAdd(ovf_n, 1);
        if (p < VO) { ovf[2 * p] = d; ovf[2 * p + 1] = s; }
    }
}

// pad x [N,6] -> x8 [N,8] (zeros in cols 6,7) for float4 row gathers
__global__ void k_pad_x(const float* __restrict__ x, float* __restrict__ x8, int N) {
    int i = blockIdx.x * blockDim.x + threadIdx.x;
    if (i >= N * 8) return;
    int n = i >> 3, c = i & 7;
    x8[i] = (c < 6) ? x[n * 6 + c] : 0.0f;
}

// ---------------- gather helpers (wave per destination) ----------------
// CHV = float4s per feature row (2 -> 8ch padded, 8 -> 32ch). q=lane%CHV, r=lane/CHV.

template <int CHV>
__device__ inline float4 gather_one(const float* __restrict__ x, const int* __restrict__ csr,
                                    size_t rowbase, int cnt_c, int lane, int q, int r) {
    const int R = 64 / CHV;
    float4 acc = make_float4(0.f, 0.f, 0.f, 0.f);
    for (int base = 0; base < cnt_c; base += 64) {
        int nb = min(64, cnt_c - base);
        int sv = (lane < nb) ? csr[rowbase + base + lane] : 0;
        int nit = (nb + R - 1) / R;
        for (int it = 0; it < nit; ++it) {
            int el = it * R + r;
            int s = __shfl(sv, el, 64);
            if (el < nb) f4add(acc, *(const float4*)(x + (size_t)s * (CHV * 4) + q * 4));
        }
    }
    return acc;
}

template <int CHV>
__device__ inline void ovf_add(const float* __restrict__ x, const int* __restrict__ ovf, int n,
                               int g, int q, int r, float4& acc) {
    for (int j = 0; j < n; ++j) {
        int d = ovf[2 * j];
        if (d == g) {
            int s = ovf[2 * j + 1];
            if (r == 0) f4add(acc, *(const float4*)(x + (size_t)s * (CHV * 4) + q * 4));
        }
    }
}

template <int CHV>
__device__ inline void reduce4(float4& a) {
#pragma unroll
    for (int st = CHV; st < 64; st <<= 1) {
        a.x += __shfl_xor(a.x, st, 64);
        a.y += __shfl_xor(a.y, st, 64);
        a.z += __shfl_xor(a.z, st, 64);
        a.w += __shfl_xor(a.w, st, 64);
    }
}

// ---------------- fused gather + per-node GEMM layers ----------------

// head: gather 8ch-padded x, K=6 -> 32 out, relu.
__global__ __launch_bounds__(256) void k_layer_head(
    const float* __restrict__ x8, const int* __restrict__ csr_i, const int* __restrict__ cnt_i,
    int Ci, const int* __restrict__ csr_t, const int* __restrict__ cnt_t, int Ct,
    const int* __restrict__ ovf_i, const int* __restrict__ ovf_t, const int* __restrict__ ovfn,
    const float* __restrict__ Wt, const float* __restrict__ Wi, const float* __restrict__ Wr,
    const float* __restrict__ b, float* __restrict__ h, int N) {
    int tid = blockIdx.x * blockDim.x + threadIdx.x;
    int g = tid >> 6;
    if (g >= N) return;
    int lane = threadIdx.x & 63;
    int q = lane & 1, r = lane >> 1;
    int cif = cnt_i[g], ci = min(cif, Ci);
    int ctf = cnt_t[g], ct = min(ctf, Ct);
    float4 ai = gather_one<2>(x8, csr_i, (size_t)g * Ci, ci, lane, q, r);
    float4 at = gather_one<2>(x8, csr_t, (size_t)g * Ct, ct, lane, q, r);
    if (cif > Ci) ovf_add<2>(x8, ovf_i, min(ovfn[0], VO), g, q, r, ai);
    if (ctf > Ct) ovf_add<2>(x8, ovf_t, min(ovfn[1], VO), g, q, r, at);
    reduce4<2>(ai);
    reduce4<2>(at);
    float inv = 1.0f / (float)max(cif, 1);
    ai.x *= inv; ai.y *= inv; ai.z *= inv; ai.w *= inv;
    // broadcast channels 0..5 (q=0 holds ch0-3 at lane 0, q=1 holds ch4-7 at lane 1)
    float a_i[6] = {__shfl(ai.x, 0, 64), __shfl(ai.y, 0, 64), __shfl(ai.z, 0, 64),
                    __shfl(ai.w, 0, 64), __shfl(ai.x, 1, 64), __shfl(ai.y, 1, 64)};
    float a_t[6] = {__shfl(at.x, 0, 64), __shfl(at.y, 0, 64), __shfl(at.z, 0, 64),
                    __shfl(at.w, 0, 64), __shfl(at.x, 1, 64), __shfl(at.y, 1, 64)};
    float vx = (lane < 6) ? x8[(size_t)g * 8 + lane] : 0.0f;
    int hc = lane & 31;
    float acc = b[hc];
#pragma unroll
    for (int k = 0; k < 6; ++k) {
        float ax = __shfl(vx, k, 64);
        acc += a_t[k] * Wt[k * 32 + hc] + a_i[k] * Wi[k * 32 + hc] + ax * Wr[k * 32 + hc];
    }
    if (lane < 32) h[(size_t)g * 32 + hc] = fmaxf(acc, 0.0f);
}

// hidden residual block: gather 32ch, K=32 -> 32 out (K split across lane halves),
// hout = relu(conv)+hin.
__global__ __launch_bounds__(256) void k_layer_blk(
    const float* __restrict__ hin, const int* __restrict__ csr_i, const int* __restrict__ cnt_i,
    int Ci, const int* __restrict__ csr_t, const int* __restrict__ cnt_t, int Ct,
    const int* __restrict__ ovf_i, const int* __restrict__ ovf_t, const int* __restrict__ ovfn,
    const float* __restrict__ Wt, const float* __restrict__ Wi, const float* __restrict__ Wr,
    const float* __restrict__ b, float* __restrict__ hout, int N) {
    int tid = blockIdx.x * blockDim.x + threadIdx.x;
    int g = tid >> 6;
    if (g >= N) return;
    int lane = threadIdx.x & 63;
    int q = lane & 7, r = lane >> 3;
    int cif = cnt_i[g], ci = min(cif, Ci);
    int ctf = cnt_t[g], ct = min(ctf, Ct);
    float4 ai = gather_one<8>(hin, csr_i, (size_t)g * Ci, ci, lane, q, r);
    float4 at = gather_one<8>(hin, csr_t, (size_t)g * Ct, ct, lane, q, r);
    if (cif > Ci) ovf_add<8>(hin, ovf_i, min(ovfn[0], VO), g, q, r, ai);
    if (ctf > Ct) ovf_add<8>(hin, ovf_t, min(ovfn[1], VO), g, q, r, at);
    reduce4<8>(ai);
    reduce4<8>(at);
    float inv = 1.0f / (float)max(cif, 1);
    int hc = lane & 31, sq = hc >> 2, sc = hc & 3;
    float vi = sel4(__shfl(ai.x, sq, 64), __shfl(ai.y, sq, 64), __shfl(ai.z, sq, 64),
                    __shfl(ai.w, sq, 64), sc) * inv;
    float vt = sel4(__shfl(at.x, sq, 64), __shfl(at.y, sq, 64), __shfl(at.z, sq, 64),
                    __shfl(at.w, sq, 64), sc);
    float vh = hin[(size_t)g * 32 + hc];
    float acc = 0.0f;
    int kbase = (lane >> 5) << 4;
#pragma unroll
    for (int it = 0; it < 16; ++it) {
        int k = kbase + it;
        float bi = __shfl(vi, k, 64), bt = __shfl(vt, k, 64), bh = __shfl(vh, k, 64);
        acc += bt * Wt[k * 32 + hc] + bi * Wi[k * 32 + hc] + bh * Wr[k * 32 + hc];
    }
    acc += __shfl_xor(acc, 32, 64);
    if (lane < 32) hout[(size_t)g * 32 + hc] = fmaxf(acc + b[hc], 0.0f) + vh;
}

// last: gather 32ch, K=32 -> 64 out, out = relu(conv) + hin @ proj.
__global__ __launch_bounds__(256) void k_layer_last(
    const float* __restrict__ hin, const int* __restrict__ csr_i, const int* __restrict__ cnt_i,
    int Ci, const int* __restrict__ csr_t, const int* __restrict__ cnt_t, int Ct,
    const int* __restrict__ ovf_i, const int* __restrict__ ovf_t, const int* __restrict__ ovfn,
    const float* __restrict__ Wt, const float* __restrict__ Wi, const float* __restrict__ Wr,
    const float* __restrict__ b, const float* __restrict__ proj, float* __restrict__ out, int N) {
    int tid = blockIdx.x * blockDim.x + threadIdx.x;
    int g = tid >> 6;
    if (g >= N) return;
    int lane = threadIdx.x & 63;
    int q = lane & 7, r = lane >> 3;
    int cif = cnt_i[g], ci = min(cif, Ci);
    int ctf = cnt_t[g], ct = min(ctf, Ct);
    float4 ai = gather_one<8>(hin, csr_i, (size_t)g * Ci, ci, lane, q, r);
    float4 at = gather_one<8>(hin, csr_t, (size_t)g * Ct, ct, lane, q, r);
    if (cif > Ci) ovf_add<8>(hin, ovf_i, min(ovfn[0], VO), g, q, r, ai);
    if (ctf > Ct) ovf_add<8>(hin, ovf_t, min(ovfn[1], VO), g, q, r, at);
    reduce4<8>(ai);
    reduce4<8>(at);
    float inv = 1.0f / (float)max(cif, 1);
    int hc = lane & 31, sq = hc >> 2, sc = hc & 3;
    float vi = sel4(__shfl(ai.x, sq, 64), __shfl(ai.y, sq, 64), __shfl(ai.z, sq, 64),
                    __shfl(ai.w, sq, 64), sc) * inv;
    float vt = sel4(__shfl(at.x, sq, 64), __shfl(at.y, sq, 64), __shfl(at.z, sq, 64),
                    __shfl(at.w, sq, 64), sc);
    float vh = hin[(size_t)g * 32 + hc];
    int ch = lane;
    float acc = b[ch];
    float accp = 0.0f;
    for (int k = 0; k < 32; ++k) {
        float bi = __shfl(vi, k, 64), bt = __shfl(vt, k, 64), bh = __shfl(vh, k, 64);
        acc += bt * Wt[k * 64 + ch] + bi * Wi[k * 64 + ch] + bh * Wr[k * 64 + ch];
        accp += bh * proj[k * 64 + ch];
    }
    out[(size_t)g * 64 + ch] = fmaxf(acc, 0.0f) + accp;
}

// ---------------- launch ----------------

static inline size_t align256(size_t x) { return (x + 255) & ~(size_t)255; }

extern "C" void kernel_launch(void* const* d_in, const int* in_sizes, int n_in,
                              void* d_out, int out_size, void* d_ws, size_t ws_size,
                              hipStream_t stream) {
    const float* x_stroke = (const float*)d_in[0];
    const int* ei_temp = (const int*)d_in[1];
    const int* ei_inter = (const int*)d_in[2];
    const float* head_Wt = (const float*)d_in[3];
    const float* head_Wi = (const float*)d_in[4];
    const float* head_Wr = (const float*)d_in[5];
    const float* head_b = (const float*)d_in[6];
    const float* blk_Wt = (const float*)d_in[7];
    const float* blk_Wi = (const float*)d_in[8];
    const float* blk_Wr = (const float*)d_in[9];
    const float* blk_b = (const float*)d_in[10];
    const float* last_Wt = (const float*)d_in[11];
    const float* last_Wi = (const float*)d_in[12];
    const float* last_Wr = (const float*)d_in[13];
    const float* last_b = (const float*)d_in[14];
    const float* last_proj = (const float*)d_in[15];

    const int N = in_sizes[0] / 6;
    const int Et = in_sizes[1] / 2;
    const int Ei = in_sizes[2] / 2;

    const int* temp_src = ei_temp;
    const int* temp_dst = ei_temp + Et;
    const int* int_src = ei_inter;
    const int* int_dst = ei_inter + Ei;

    // bucket shift: smallest with NB <= 1024
    int shift = 7;
    while ((((N - 1) >> shift) + 1) > 1024) ++shift;
    const int NB = ((N - 1) >> shift) + 1;

    // ---- workspace carve-up ----
    char* p = (char*)d_ws;
    size_t off = 0;
    auto carve = [&](size_t bytes) {
        char* r = p + off;
        off = align256(off + bytes);
        return r;
    };
    int* cnt_i = (int*)carve((size_t)N * 4);
    int* cnt_t = (int*)carve((size_t)N * 4);
    int* ovfn = (int*)carve(2 * 4);
    int* ovf_i = (int*)carve((size_t)VO * 8);
    int* ovf_t = (int*)carve((size_t)VO * 8);
    int* gh = (int*)carve((size_t)NB * 4);
    int* boff = (int*)carve((size_t)(NB + 1) * 4);
    int* cur = (int*)carve((size_t)NB * 4);
    float* x8 = (float*)carve((size_t)N * 8 * 4);
    float* bufA = (float*)carve((size_t)N * 32 * 4);
    float* bufD = (float*)carve((size_t)N * 32 * 4);
    int2* ebuf = (int2*)carve((size_t)Ei * 8);
    int Ct = 16, Ci = 64;
    {
        size_t avail = (ws_size > off) ? (ws_size - off) : 0;
        size_t cap = avail / ((size_t)N * 4);
        if ((size_t)(Ct + Ci) > cap) {
            Ct = 8;
            Ci = (cap > (size_t)Ct) ? (int)(cap - Ct) : 4;
            if (Ci > 64) Ci = 64;
        }
    }
    int* csr_t = (int*)carve((size_t)N * Ct * 4);
    int* csr_i = (int*)carve((size_t)N * Ci * 4);

    const int B = 256;
    auto blocks = [&](long long work) { return (int)((work + B - 1) / B); };

    // ---- CSR builds ----
    hipMemsetAsync(cnt_i, 0, (size_t)N * 4, stream);
    hipMemsetAsync(cnt_t, 0, (size_t)N * 4, stream);
    hipMemsetAsync(ovfn, 0, 2 * 4, stream);
    hipMemsetAsync(gh, 0, (size_t)NB * 4, stream);

    k_hist<<<256, B, 0, stream>>>(int_dst, Ei, gh, NB, shift);
    k_scan_b<<<1, 1024, 0, stream>>>(gh, NB, boff, cur);
    k_scatter<<<blocks((long long)Ei / EPT + 1), B, 0, stream>>>(int_src, int_dst, Ei, shift, NB,
                                                                 cur, ebuf);
    k_fill3<<<NB, B, 0, stream>>>(ebuf, boff, NB, cnt_i, csr_i, Ci, ovf_i, &ovfn[0]);
    k_fill2<<<blocks(Et), B, 0, stream>>>(temp_src, temp_dst, Et, cnt_t, csr_t, Ct, ovf_t, &ovfn[1]);
    k_pad_x<<<blocks((long long)N * 8), B, 0, stream>>>(x_stroke, x8, N);

    // ---- head ----
    k_layer_head<<<blocks((long long)N * 64), B, 0, stream>>>(
        x8, csr_i, cnt_i, Ci, csr_t, cnt_t, Ct, ovf_i, ovf_t, ovfn, head_Wt, head_Wi, head_Wr,
        head_b, bufA, N);

    // ---- 3 hidden residual blocks ----
    float* hin = bufA;
    float* hout = bufD;
    for (int i = 0; i < 3; ++i) {
        k_layer_blk<<<blocks((long long)N * 64), B, 0, stream>>>(
            hin, csr_i, cnt_i, Ci, csr_t, cnt_t, Ct, ovf_i, ovf_t, ovfn,
            blk_Wt + (size_t)i * 32 * 32, blk_Wi + (size_t)i * 32 * 32,
            blk_Wr + (size_t)i * 32 * 32, blk_b + (size_t)i * 32, hout, N);
        float* t = hin; hin = hout; hout = t;
    }

    // ---- last ----
    k_layer_last<<<blocks((long long)N * 64), B, 0, stream>>>(
        hin, csr_i, cnt_i, Ci, csr_t, cnt_t, Ct, ovf_i, ovf_t, ovfn, last_Wt, last_Wi, last_Wr,
        last_b, last_proj, (float*)d_out, N);
}

// Round 4
// 759.560 us; speedup vs baseline: 2.0851x; 1.0083x over previous
//
#include <hip/hip_runtime.h>

// Hetero-GNN: 5 layers of relu(segsum_temp(x) @ Wt + segmean_inter(x) @ Wi + x @ Wr + b)
// with aggregation commuted past the matmuls (aggregate RAW features, then one
// fused per-node mini-GEMM inside the SAME kernel as the gather).
//
// Inter relation (3.2M edges): padded CSR built via destination BINNING (hist ->
// scan -> bucket-sorted scatter -> per-bucket fill) to avoid scatter write-amp.
// Temp relation (100k edges): one-pass atomic fill.
// Gather inner loop issues U=4 independent row loads per group (explicit unroll)
// to get memory-level parallelism — the R3 version had VGPR=24 and one load in
// flight (vmcnt(0) per row-iteration = latency-bound).

#define VO 8192   // overflow list capacity (pairs) per relation
#define EPT 16    // edges per thread in k_scatter

__device__ inline void f4add(float4& a, const float4& v) {
    a.x += v.x; a.y += v.y; a.z += v.z; a.w += v.w;
}

__device__ inline float sel4(float a, float b, float c, float d, int k) {
    return (k & 2) ? ((k & 1) ? d : c) : ((k & 1) ? b : a);
}

// ---------------- inter CSR build: hist -> scan -> scatter -> fill ----------------

__global__ void k_hist(const int* __restrict__ dst, int E, int* __restrict__ gh,
                       int NB, int shift) {
    __shared__ int sh[1024];
    for (int j = threadIdx.x; j < NB; j += blockDim.x) sh[j] = 0;
    __syncthreads();
    for (int i = blockIdx.x * blockDim.x + threadIdx.x; i < E; i += gridDim.x * blockDim.x)
        atomicAdd(&sh[dst[i] >> shift], 1);
    __syncthreads();
    for (int j = threadIdx.x; j < NB; j += blockDim.x)
        if (sh[j]) atomicAdd(&gh[j], sh[j]);
}

__global__ void k_scan_b(const int* __restrict__ gh, int NB, int* __restrict__ boff,
                         int* __restrict__ cur) {
    __shared__ int sh[1024];
    int t = threadIdx.x;
    sh[t] = (t < NB) ? gh[t] : 0;
    __syncthreads();
    for (int off = 1; off < 1024; off <<= 1) {
        int v = (t >= off) ? sh[t - off] : 0;
        __syncthreads();
        sh[t] += v;
        __syncthreads();
    }
    if (t < NB) {
        int ex = t ? sh[t - 1] : 0;
        boff[t] = ex;
        cur[t] = ex;
    }
    if (t == 0) boff[NB] = sh[NB - 1];
}

__global__ void k_scatter(const int* __restrict__ src, const int* __restrict__ dst, int E,
                          int shift, int NB, int* __restrict__ cur, int2* __restrict__ ebuf) {
    __shared__ int lh[1024];
    __shared__ int lb[1024];
    int lo = blockIdx.x * (blockDim.x * EPT);
    for (int j = threadIdx.x; j < NB; j += blockDim.x) lh[j] = 0;
    __syncthreads();
    int s[EPT], d[EPT], rk[EPT];
#pragma unroll
    for (int u = 0; u < EPT; ++u) {
        int e = lo + u * blockDim.x + threadIdx.x;
        if (e < E) {
            s[u] = src[e];
            d[u] = dst[e];
            rk[u] = atomicAdd(&lh[d[u] >> shift], 1);
        }
    }
    __syncthreads();
    for (int j = threadIdx.x; j < NB; j += blockDim.x) {
        int c = lh[j];
        lb[j] = c ? atomicAdd(&cur[j], c) : 0;
    }
    __syncthreads();
#pragma unroll
    for (int u = 0; u < EPT; ++u) {
        int e = lo + u * blockDim.x + threadIdx.x;
        if (e < E) ebuf[lb[d[u] >> shift] + rk[u]] = make_int2(s[u], d[u]);
    }
}

__global__ void k_fill3(const int2* __restrict__ ebuf, const int* __restrict__ boff, int NB,
                        int* __restrict__ cnt, int* __restrict__ csr, int Ci,
                        int* __restrict__ ovf, int* __restrict__ ovf_n) {
    int b = blockIdx.x;
    if (b >= NB) return;
    int lo = boff[b], hi = boff[b + 1];
    for (int e = lo + threadIdx.x; e < hi; e += blockDim.x) {
        int2 sd = ebuf[e];
        int slot = atomicAdd(&cnt[sd.y], 1);
        if (slot < Ci) {
            csr[(size_t)sd.y * Ci + slot] = sd.x;
        } else {
            int p = atomicAdd(ovf_n, 1);
            if (p < VO) { ovf[2 * p] = sd.y; ovf[2 * p + 1] = sd.x; }
        }
    }
}

__global__ void k_fill2(const int* __restrict__ src, const int* __restrict__ dst, int E,
                        int* __restrict__ cnt, int* __restrict__ csr, int C,
                        int* __restrict__ ovf, int* __restrict__ ovf_n) {
    int i = blockIdx.x * blockDim.x + threadIdx.x;
    if (i >= E) return;
    int s = src[i];
    int d = dst[i];
    int slot = atomicAdd(&cnt[d], 1);
    if (slot < C) {
        csr[(size_t)d * C + slot] = s;
    } else {
        int p = atomicAdd(ovf_n, 1);
        if (p < VO) { ovf[2 * p] = d; ovf[2 * p + 1] = s; }
    }
}

__global__ void k_pad_x(const float* __restrict__ x, float* __restrict__ x8, int N) {
    int i = blockIdx.x * blockDim.x + threadIdx.x;
    if (i >= N * 8) return;
    int n = i >> 3, c = i & 7;
    x8[i] = (c < 6) ? x[n * 6 + c] : 0.0f;
}

// ---------------- gather helpers (wave per destination) ----------------
// CHV = float4s per feature row (2 -> 8ch padded, 8 -> 32ch). q=lane%CHV, r=lane/CHV.
// g_grp: U independent row loads issued before any use (MLP). Invalid lanes of sv
// hold 0 (safe row); masked tail zeroes their contribution via fma mask.

template <int CHV, int U, bool MASK>
__device__ inline void g_grp(const float* __restrict__ x, int sv, int it0, int nb,
                             int q, int r, float4& acc) {
    const int R = 64 / CHV;
    int s[U];
    float4 v[U];
#pragma unroll
    for (int u = 0; u < U; ++u) s[u] = __shfl(sv, (it0 + u) * R + r, 64);
#pragma unroll
    for (int u = 0; u < U; ++u) v[u] = *(const float4*)(x + (size_t)s[u] * (CHV * 4) + q * 4);
#pragma unroll
    for (int u = 0; u < U; ++u) {
        if (MASK) {
            float m = ((it0 + u) * R + r < nb) ? 1.0f : 0.0f;
            acc.x = fmaf(m, v[u].x, acc.x);
            acc.y = fmaf(m, v[u].y, acc.y);
            acc.z = fmaf(m, v[u].z, acc.z);
            acc.w = fmaf(m, v[u].w, acc.w);
        } else {
            f4add(acc, v[u]);
        }
    }
}

template <int CHV, int U>
__device__ inline float4 gather_one(const float* __restrict__ x, const int* __restrict__ csr,
                                    size_t rowbase, int cnt_c, int lane, int q, int r) {
    const int R = 64 / CHV;
    float4 acc = make_float4(0.f, 0.f, 0.f, 0.f);
    for (int base = 0; base < cnt_c; base += 64) {
        int nb = min(64, cnt_c - base);
        int sv = (lane < nb) ? csr[rowbase + base + lane] : 0;
        int it = 0;
        while ((it + U) * R <= nb) {           // full groups, no mask
            g_grp<CHV, U, false>(x, sv, it, nb, q, r, acc);
            it += U;
        }
        if (it * R < nb)                       // one masked tail group
            g_grp<CHV, U, true>(x, sv, it, nb, q, r, acc);
    }
    return acc;
}

template <int CHV>
__device__ inline void ovf_add(const float* __restrict__ x, const int* __restrict__ ovf, int n,
                               int g, int q, int r, float4& acc) {
    for (int j = 0; j < n; ++j) {
        int d = ovf[2 * j];
        if (d == g) {
            int s = ovf[2 * j + 1];
            if (r == 0) f4add(acc, *(const float4*)(x + (size_t)s * (CHV * 4) + q * 4));
        }
    }
}

template <int CHV>
__device__ inline void reduce4(float4& a) {
#pragma unroll
    for (int st = CHV; st < 64; st <<= 1) {
        a.x += __shfl_xor(a.x, st, 64);
        a.y += __shfl_xor(a.y, st, 64);
        a.z += __shfl_xor(a.z, st, 64);
        a.w += __shfl_xor(a.w, st, 64);
    }
}

// ---------------- fused gather + per-node GEMM layers ----------------

__global__ __launch_bounds__(256) void k_layer_head(
    const float* __restrict__ x8, const int* __restrict__ csr_i, const int* __restrict__ cnt_i,
    int Ci, const int* __restrict__ csr_t, const int* __restrict__ cnt_t, int Ct,
    const int* __restrict__ ovf_i, const int* __restrict__ ovf_t, const int* __restrict__ ovfn,
    const float* __restrict__ Wt, const float* __restrict__ Wi, const float* __restrict__ Wr,
    const float* __restrict__ b, float* __restrict__ h, int N) {
    int tid = blockIdx.x * blockDim.x + threadIdx.x;
    int g = tid >> 6;
    if (g >= N) return;
    int lane = threadIdx.x & 63;
    int q = lane & 1, r = lane >> 1;
    int cif = cnt_i[g], ci = min(cif, Ci);
    int ctf = cnt_t[g], ct = min(ctf, Ct);
    float4 ai = gather_one<2, 2>(x8, csr_i, (size_t)g * Ci, ci, lane, q, r);
    float4 at = gather_one<2, 1>(x8, csr_t, (size_t)g * Ct, ct, lane, q, r);
    if (cif > Ci) ovf_add<2>(x8, ovf_i, min(ovfn[0], VO), g, q, r, ai);
    if (ctf > Ct) ovf_add<2>(x8, ovf_t, min(ovfn[1], VO), g, q, r, at);
    reduce4<2>(ai);
    reduce4<2>(at);
    float inv = 1.0f / (float)max(cif, 1);
    ai.x *= inv; ai.y *= inv; ai.z *= inv; ai.w *= inv;
    float a_i[6] = {__shfl(ai.x, 0, 64), __shfl(ai.y, 0, 64), __shfl(ai.z, 0, 64),
                    __shfl(ai.w, 0, 64), __shfl(ai.x, 1, 64), __shfl(ai.y, 1, 64)};
    float a_t[6] = {__shfl(at.x, 0, 64), __shfl(at.y, 0, 64), __shfl(at.z, 0, 64),
                    __shfl(at.w, 0, 64), __shfl(at.x, 1, 64), __shfl(at.y, 1, 64)};
    float vx = (lane < 6) ? x8[(size_t)g * 8 + lane] : 0.0f;
    int hc = lane & 31;
    float acc = b[hc];
#pragma unroll
    for (int k = 0; k < 6; ++k) {
        float ax = __shfl(vx, k, 64);
        acc += a_t[k] * Wt[k * 32 + hc] + a_i[k] * Wi[k * 32 + hc] + ax * Wr[k * 32 + hc];
    }
    if (lane < 32) h[(size_t)g * 32 + hc] = fmaxf(acc, 0.0f);
}

__global__ __launch_bounds__(256) void k_layer_blk(
    const float* __restrict__ hin, const int* __restrict__ csr_i, const int* __restrict__ cnt_i,
    int Ci, const int* __restrict__ csr_t, const int* __restrict__ cnt_t, int Ct,
    const int* __restrict__ ovf_i, const int* __restrict__ ovf_t, const int* __restrict__ ovfn,
    const float* __restrict__ Wt, const float* __restrict__ Wi, const float* __restrict__ Wr,
    const float* __restrict__ b, float* __restrict__ hout, int N) {
    int tid = blockIdx.x * blockDim.x + threadIdx.x;
    int g = tid >> 6;
    if (g >= N) return;
    int lane = threadIdx.x & 63;
    int q = lane & 7, r = lane >> 3;
    int cif = cnt_i[g], ci = min(cif, Ci);
    int ctf = cnt_t[g], ct = min(ctf, Ct);
    float4 ai = gather_one<8, 4>(hin, csr_i, (size_t)g * Ci, ci, lane, q, r);
    float4 at = gather_one<8, 1>(hin, csr_t, (size_t)g * Ct, ct, lane, q, r);
    if (cif > Ci) ovf_add<8>(hin, ovf_i, min(ovfn[0], VO), g, q, r, ai);
    if (ctf > Ct) ovf_add<8>(hin, ovf_t, min(ovfn[1], VO), g, q, r, at);
    reduce4<8>(ai);
    reduce4<8>(at);
    float inv = 1.0f / (float)max(cif, 1);
    int hc = lane & 31, sq = hc >> 2, sc = hc & 3;
    float vi = sel4(__shfl(ai.x, sq, 64), __shfl(ai.y, sq, 64), __shfl(ai.z, sq, 64),
                    __shfl(ai.w, sq, 64), sc) * inv;
    float vt = sel4(__shfl(at.x, sq, 64), __shfl(at.y, sq, 64), __shfl(at.z, sq, 64),
                    __shfl(at.w, sq, 64), sc);
    float vh = hin[(size_t)g * 32 + hc];
    float acc = 0.0f;
    int kbase = (lane >> 5) << 4;
#pragma unroll
    for (int it = 0; it < 16; ++it) {
        int k = kbase + it;
        float bi = __shfl(vi, k, 64), bt = __shfl(vt, k, 64), bh = __shfl(vh, k, 64);
        acc += bt * Wt[k * 32 + hc] + bi * Wi[k * 32 + hc] + bh * Wr[k * 32 + hc];
    }
    acc += __shfl_xor(acc, 32, 64);
    if (lane < 32) hout[(size_t)g * 32 + hc] = fmaxf(acc + b[hc], 0.0f) + vh;
}

__global__ __launch_bounds__(256) void k_layer_last(
    const float* __restrict__ hin, const int* __restrict__ csr_i, const int* __restrict__ cnt_i,
    int Ci, const int* __restrict__ csr_t, const int* __restrict__ cnt_t, int Ct,
    const int* __restrict__ ovf_i, const int* __restrict__ ovf_t, const int* __restrict__ ovfn,
    const float* __restrict__ Wt, const float* __restrict__ Wi, const float* __restrict__ Wr,
    const float* __restrict__ b, const float* __restrict__ proj, float* __restrict__ out, int N) {
    int tid = blockIdx.x * blockDim.x + threadIdx.x;
    int g = tid >> 6;
    if (g >= N) return;
    int lane = threadIdx.x & 63;
    int q = lane & 7, r = lane >> 3;
    int cif = cnt_i[g], ci = min(cif, Ci);
    int ctf = cnt_t[g], ct = min(ctf, Ct);
    float4 ai = gather_one<8, 4>(hin, csr_i, (size_t)g * Ci, ci, lane, q, r);
    float4 at = gather_one<8, 1>(hin, csr_t, (size_t)g * Ct, ct, lane, q, r);
    if (cif > Ci) ovf_add<8>(hin, ovf_i, min(ovfn[0], VO), g, q, r, ai);
    if (ctf > Ct) ovf_add<8>(hin, ovf_t, min(ovfn[1], VO), g, q, r, at);
    reduce4<8>(ai);
    reduce4<8>(at);
    float inv = 1.0f / (float)max(cif, 1);
    int hc = lane & 31, sq = hc >> 2, sc = hc & 3;
    float vi = sel4(__shfl(ai.x, sq, 64), __shfl(ai.y, sq, 64), __shfl(ai.z, sq, 64),
                    __shfl(ai.w, sq, 64), sc) * inv;
    float vt = sel4(__shfl(at.x, sq, 64), __shfl(at.y, sq, 64), __shfl(at.z, sq, 64),
                    __shfl(at.w, sq, 64), sc);
    float vh = hin[(size_t)g * 32 + hc];
    int ch = lane;
    float acc = b[ch];
    float accp = 0.0f;
    for (int k = 0; k < 32; ++k) {
        float bi = __shfl(vi, k, 64), bt = __shfl(vt, k, 64), bh = __shfl(vh, k, 64);
        acc += bt * Wt[k * 64 + ch] + bi * Wi[k * 64 + ch] + bh * Wr[k * 64 + ch];
        accp += bh * proj[k * 64 + ch];
    }
    out[(size_t)g * 64 + ch] = fmaxf(acc, 0.0f) + accp;
}

// ---------------- launch ----------------

static inline size_t align256(size_t x) { return (x + 255) & ~(size_t)255; }

extern "C" void kernel_launch(void* const* d_in, const int* in_sizes, int n_in,
                              void* d_out, int out_size, void* d_ws, size_t ws_size,
                              hipStream_t stream) {
    const float* x_stroke = (const float*)d_in[0];
    const int* ei_temp = (const int*)d_in[1];
    const int* ei_inter = (const int*)d_in[2];
    const float* head_Wt = (const float*)d_in[3];
    const float* head_Wi = (const float*)d_in[4];
    const float* head_Wr = (const float*)d_in[5];
    const float* head_b = (const float*)d_in[6];
    const float* blk_Wt = (const float*)d_in[7];
    const float* blk_Wi = (const float*)d_in[8];
    const float* blk_Wr = (const float*)d_in[9];
    const float* blk_b = (const float*)d_in[10];
    const float* last_Wt = (const float*)d_in[11];
    const float* last_Wi = (const float*)d_in[12];
    const float* last_Wr = (const float*)d_in[13];
    const float* last_b = (const float*)d_in[14];
    const float* last_proj = (const float*)d_in[15];

    const int N = in_sizes[0] / 6;
    const int Et = in_sizes[1] / 2;
    const int Ei = in_sizes[2] / 2;

    const int* temp_src = ei_temp;
    const int* temp_dst = ei_temp + Et;
    const int* int_src = ei_inter;
    const int* int_dst = ei_inter + Ei;

    int shift = 7;
    while ((((N - 1) >> shift) + 1) > 1024) ++shift;
    const int NB = ((N - 1) >> shift) + 1;

    char* p = (char*)d_ws;
    size_t off = 0;
    auto carve = [&](size_t bytes) {
        char* r = p + off;
        off = align256(off + bytes);
        return r;
    };
    int* cnt_i = (int*)carve((size_t)N * 4);
    int* cnt_t = (int*)carve((size_t)N * 4);
    int* ovfn = (int*)carve(2 * 4);
    int* ovf_i = (int*)carve((size_t)VO * 8);
    int* ovf_t = (int*)carve((size_t)VO * 8);
    int* gh = (int*)carve((size_t)NB * 4);
    int* boff = (int*)carve((size_t)(NB + 1) * 4);
    int* cur = (int*)carve((size_t)NB * 4);
    float* x8 = (float*)carve((size_t)N * 8 * 4);
    float* bufA = (float*)carve((size_t)N * 32 * 4);
    float* bufD = (float*)carve((size_t)N * 32 * 4);
    int2* ebuf = (int2*)carve((size_t)Ei * 8);
    int Ct = 16, Ci = 64;
    {
        size_t avail = (ws_size > off) ? (ws_size - off) : 0;
        size_t cap = avail / ((size_t)N * 4);
        if ((size_t)(Ct + Ci) > cap) {
            Ct = 8;
            Ci = (cap > (size_t)Ct) ? (int)(cap - Ct) : 4;
            if (Ci > 64) Ci = 64;
        }
    }
    int* csr_t = (int*)carve((size_t)N * Ct * 4);
    int* csr_i = (int*)carve((size_t)N * Ci * 4);

    const int B = 256;
    auto blocks = [&](long long work) { return (int)((work + B - 1) / B); };

    hipMemsetAsync(cnt_i, 0, (size_t)N * 4, stream);
    hipMemsetAsync(cnt_t, 0, (size_t)N * 4, stream);
    hipMemsetAsync(ovfn, 0, 2 * 4, stream);
    hipMemsetAsync(gh, 0, (size_t)NB * 4, stream);

    k_hist<<<256, B, 0, stream>>>(int_dst, Ei, gh, NB, shift);
    k_scan_b<<<1, 1024, 0, stream>>>(gh, NB, boff, cur);
    k_scatter<<<blocks((long long)Ei / EPT + 1), B, 0, stream>>>(int_src, int_dst, Ei, shift, NB,
                                                                 cur, ebuf);
    k_fill3<<<NB, B, 0, stream>>>(ebuf, boff, NB, cnt_i, csr_i, Ci, ovf_i, &ovfn[0]);
    k_fill2<<<blocks(Et), B, 0, stream>>>(temp_src, temp_dst, Et, cnt_t, csr_t, Ct, ovf_t, &ovfn[1]);
    k_pad_x<<<blocks((long long)N * 8), B, 0, stream>>>(x_stroke, x8, N);

    k_layer_head<<<blocks((long long)N * 64), B, 0, stream>>>(
        x8, csr_i, cnt_i, Ci, csr_t, cnt_t, Ct, ovf_i, ovf_t, ovfn, head_Wt, head_Wi, head_Wr,
        head_b, bufA, N);

    float* hin = bufA;
    float* hout = bufD;
    for (int i = 0; i < 3; ++i) {
        k_layer_blk<<<blocks((long long)N * 64), B, 0, stream>>>(
            hin, csr_i, cnt_i, Ci, csr_t, cnt_t, Ct, ovf_i, ovf_t, ovfn,
            blk_Wt + (size_t)i * 32 * 32, blk_Wi + (size_t)i * 32 * 32,
            blk_Wr + (size_t)i * 32 * 32, blk_b + (size_t)i * 32, hout, N);
        float* t = hin; hin = hout; hout = t;
    }

    k_layer_last<<<blocks((long long)N * 64), B, 0, stream>>>(
        hin, csr_i, cnt_i, Ci, csr_t, cnt_t, Ct, ovf_i, ovf_t, ovfn, last_Wt, last_Wi, last_Wr,
        last_b, last_proj, (float*)d_out, N);
}